// Round 10
// baseline (435.947 us; speedup 1.0000x reference)
//
#include <hip/hip_runtime.h>
#include <math.h>

// ---------------- problem constants ----------------
constexpr int Bc  = 4;
constexpr int Hc  = 96;
constexpr int Wc  = 320;
constexpr int HWc = Hc * Wc;           // 30720
constexpr int NPIX = Bc * HWc;         // 122880

typedef __attribute__((ext_vector_type(8))) short short8;   // 8 x bf16 fragment
typedef __attribute__((ext_vector_type(4))) float f32x4;    // mfma acc

// ---------------- workspace byte offsets ----------------
constexpr size_t B_W1   = 0;                    // bf16 [9][64co][64ci]   73728 B
constexpr size_t B_W2   = 73728;                // bf16 [9][32co][64ci]   36864 B
constexpr size_t B_WD   = 110592;               // bf16 [9][64o][64c]     73728 B
constexpr size_t B_WF   = 184320;               // bf16 [2][9][64co][64ci]147456 B
constexpr size_t B_AB   = 331776;               // f32 A1,B1,A2,B2        1024 B
constexpr size_t B_RGBT = 332800;               // bf16 [pix][64]         15728640 B
constexpr size_t B_DEPT = 16061440;             // bf16 [pix][64]  (later reused as hT)
constexpr size_t B_TT   = 31790080;             // bf16 [pix][64]  (later reused as fdreluT)
constexpr size_t B_HEAD = 47518720;             // f32  [pix][32]         15728640 B

// ---------------- helpers ----------------
static __device__ __forceinline__ unsigned short f2bf(float f) {
    unsigned u = __builtin_bit_cast(unsigned, f);
    u = (u + 0x7fffu + ((u >> 16) & 1u)) >> 16;   // RNE
    return (unsigned short)u;
}
static __device__ __forceinline__ float bf2f(unsigned short h) {
    unsigned u = ((unsigned)h) << 16;
    return __builtin_bit_cast(float, u);
}
// XCD-aware block swizzle: grid divisible by 8; each XCD gets contiguous chunk.
static __device__ __forceinline__ int swz_blk(int bid, int chunk) {
    return (bid & 7) * chunk + (bid >> 3);
}

// ---------------- prep: weights + BN folds ----------------
__global__ void prep_w(const float* __restrict__ w1, const float* __restrict__ b1,
                       const float* __restrict__ g1, const float* __restrict__ be1,
                       const float* __restrict__ m1, const float* __restrict__ v1,
                       const float* __restrict__ w2,
                       const float* __restrict__ wd,
                       const float* __restrict__ wf, const float* __restrict__ bf1,
                       const float* __restrict__ g2, const float* __restrict__ be2,
                       const float* __restrict__ m2, const float* __restrict__ v2,
                       char* __restrict__ ws) {
    int tid = blockIdx.x * blockDim.x + threadIdx.x;
    int stride = gridDim.x * blockDim.x;
    unsigned short* W1 = (unsigned short*)(ws + B_W1);
    unsigned short* W2 = (unsigned short*)(ws + B_W2);
    unsigned short* WD = (unsigned short*)(ws + B_WD);
    unsigned short* WF = (unsigned short*)(ws + B_WF);
    float* AB = (float*)(ws + B_AB);
    for (int i = tid; i < 36864; i += stride) {         // W1p [kk][co][ci]
        int ci = i & 63, co = (i >> 6) & 63, kk = i >> 12;
        W1[i] = f2bf(w1[(co * 64 + ci) * 9 + kk]);
    }
    for (int i = tid; i < 18432; i += stride) {         // W2p [kk][32co][ci]
        int ci = i & 63, co = (i >> 6) & 31, kk = i >> 11;
        W2[i] = (co < 27) ? f2bf(w2[(co * 64 + ci) * 9 + kk]) : (unsigned short)0;
    }
    for (int i = tid; i < 36864; i += stride) {         // Wdp [kk][o][c]
        int c = i & 63, o = (i >> 6) & 63, kk = i >> 12;
        WD[i] = f2bf(wd[(o * 64 + c) * 9 + kk]);
    }
    for (int i = tid; i < 73728; i += stride) {         // Wfp [half][kk][co][ci]
        int ci = i & 63, co = (i >> 6) & 63, r = i >> 12;
        int kk = r % 9, h = r / 9;
        WF[i] = f2bf(wf[(co * 128 + h * 64 + ci) * 9 + kk]);
    }
    if (tid < 64) {
        float s1 = g1[tid] / sqrtf(v1[tid] + 1e-5f);
        AB[tid]        = s1;
        AB[64 + tid]   = b1[tid] * s1 + be1[tid] - m1[tid] * s1;
        float s2 = g2[tid] / sqrtf(v2[tid] + 1e-5f);
        AB[128 + tid]  = s2;
        AB[192 + tid]  = bf1[tid] * s2 + be2[tid] - m2[tid] * s2;
    }
}

// ---- prep_x2: coalesced f32 read -> LDS transpose -> coalesced bf16 write ----
// One block = 64 consecutive pixels (never crosses batch; 30720 % 64 == 0).
__global__ __launch_bounds__(256) void prep_x2(const float* __restrict__ rgb,
                                               const float* __restrict__ dep,
                                               unsigned short* __restrict__ rgbT,
                                               unsigned short* __restrict__ depT) {
    __shared__ unsigned short tr[64 * 66];     // [p][ch], stride 66 (bank-safe both sides)
    int pg0 = blockIdx.x * 64;
    int b = pg0 / HWc, pix0 = pg0 % HWc;
    const float* srcs[2] = { rgb, dep };
    unsigned short* dsts[2] = { rgbT, depT };
#pragma unroll
    for (int which = 0; which < 2; ++which) {
        if (which) __syncthreads();            // WAR vs previous read phase
        const float* src = srcs[which];
#pragma unroll
        for (int it = 0; it < 16; ++it) {
            int idx = it * 256 + threadIdx.x;
            int p = idx & 63, ch = idx >> 6;
            float v = src[((size_t)b * 64 + ch) * HWc + pix0 + p];
            tr[p * 66 + ch] = f2bf(v);
        }
        __syncthreads();
        unsigned short* dst = dsts[which];
#pragma unroll
        for (int it = 0; it < 2; ++it) {
            int q = it * 256 + threadIdx.x;
            int p = q >> 3, g = q & 7;
            const char* basep = (const char*)tr + p * 132 + g * 16;   // 4-aligned
            uint4 u;
            u.x = *(const unsigned*)(basep + 0);
            u.y = *(const unsigned*)(basep + 4);
            u.z = *(const unsigned*)(basep + 8);
            u.w = *(const unsigned*)(basep + 12);
            *(uint4*)(dst + (size_t)(pg0 + p) * 64 + g * 8) = u;
        }
    }
}

// ---------------- LDS staging: 6-row halo tile (convs) ----------------
// LDS layout: [6 rows][66 xx][64 ci] bf16, byte addr ^= ((xx&7)<<4)
static __device__ __forceinline__ void stage6(const unsigned short* __restrict__ src,
                                              int b, int y0, int x0,
                                              unsigned short* lds, bool do_relu) {
#pragma unroll
    for (int it = 0; it < 13; ++it) {
        int i = threadIdx.x + it * 256;
        if (i < 3168) {                       // 6*66*8
            int g = i & 7;
            int xx = (i >> 3) % 66;
            int row = (i >> 3) / 66;
            int y = y0 - 1 + row, x = x0 - 1 + xx;
            short8 v = (short8)0;
            if ((unsigned)y < 96u && (unsigned)x < 320u) {
                v = *(const short8*)(src + ((size_t)(b * HWc + y * Wc + x)) * 64 + g * 8);
            }
            if (do_relu) {
#pragma unroll
                for (int j = 0; j < 8; ++j) {
                    short s = v[j];
                    v[j] = (s & (short)0x8000) ? (short)0 : s;
                }
            }
            int byte = ((row * 66 + xx) * 64 + g * 8) * 2;
            byte ^= ((xx & 7) << 4);
            *(short8*)((char*)lds + byte) = v;
        }
    }
}

static __device__ __forceinline__ short8 read_b6(const unsigned short* lds, int row, int xx, int cofs) {
    int byte = ((row * 66 + xx) * 64 + cofs) * 2;
    byte ^= ((xx & 7) << 4);
    return *(const short8*)((const char*)lds + byte);
}

// ---------------- conv1: 64->64 + BN, rgbT -> tT  (4-row blocks) ----------------
__global__ __launch_bounds__(256) void conv1_m(const unsigned short* __restrict__ rgbT,
                                               const char* __restrict__ ws,
                                               unsigned short* __restrict__ tT) {
    __shared__ __align__(16) unsigned short xls[6 * 66 * 64];
    const unsigned short* W1 = (const unsigned short*)(ws + B_W1);
    const float* AB = (const float*)(ws + B_AB);
    int blk = swz_blk(blockIdx.x, 60);        // 480 blocks
    int xt = blk % 5, yt = (blk / 5) % 24, b = blk / 120;
    int x0 = xt * 64, y0 = yt * 4;
    stage6(rgbT, b, y0, x0, xls, false);
    __syncthreads();
    int lane = threadIdx.x & 63, w = threadIdx.x >> 6;
    int pl = lane & 15, q4 = lane >> 4;
    int p = w * 16 + pl;
    f32x4 acc[4][4];                          // [row][cp]
#pragma unroll
    for (int r = 0; r < 4; ++r)
#pragma unroll
        for (int cp = 0; cp < 4; ++cp) acc[r][cp] = (f32x4)0.f;
#pragma unroll
    for (int kk = 0; kk < 9; ++kk) {
        int dy = kk / 3, dx = kk % 3;
        int xx = p + dx;
#pragma unroll
        for (int ch = 0; ch < 2; ++ch) {
            short8 bfr[4];
#pragma unroll
            for (int r = 0; r < 4; ++r) bfr[r] = read_b6(xls, dy + r, xx, ch * 32 + q4 * 8);
#pragma unroll
            for (int cp = 0; cp < 4; ++cp) {
                short8 afr = *(const short8*)(W1 + ((kk * 64 + cp * 16 + pl) * 64 + ch * 32 + q4 * 8));
#pragma unroll
                for (int r = 0; r < 4; ++r)
                    acc[r][cp] = __builtin_amdgcn_mfma_f32_16x16x32_bf16(afr, bfr[r], acc[r][cp], 0, 0, 0);
            }
        }
    }
#pragma unroll
    for (int r = 0; r < 4; ++r) {
        size_t pglob = (size_t)(b * HWc + (y0 + r) * Wc + x0 + p);
#pragma unroll
        for (int cp = 0; cp < 4; ++cp) {
            int co0 = cp * 16 + q4 * 4;
            f32x4 a1 = *(const f32x4*)(AB + co0);
            f32x4 b1 = *(const f32x4*)(AB + 64 + co0);
            unsigned short h4[4];
#pragma unroll
            for (int j = 0; j < 4; ++j) h4[j] = f2bf(fmaf(acc[r][cp][j], a1[j], b1[j]));
            uint2 u;
            u.x = (unsigned)h4[0] | ((unsigned)h4[1] << 16);
            u.y = (unsigned)h4[2] | ((unsigned)h4[3] << 16);
            *(uint2*)(tT + pglob * 64 + co0) = u;
        }
    }
}

// ---------------- conv2: 64->27(pad32), tT -> headT (f32)  (4-row blocks) ----------------
__global__ __launch_bounds__(256) void conv2_m(const char* __restrict__ ws,
                                               const float* __restrict__ b2,
                                               float* __restrict__ headT,
                                               const unsigned short* __restrict__ tT) {
    __shared__ __align__(16) unsigned short xls[6 * 66 * 64];
    const unsigned short* W2 = (const unsigned short*)(ws + B_W2);
    int blk = swz_blk(blockIdx.x, 60);
    int xt = blk % 5, yt = (blk / 5) % 24, b = blk / 120;
    int x0 = xt * 64, y0 = yt * 4;
    stage6(tT, b, y0, x0, xls, false);
    __syncthreads();
    int lane = threadIdx.x & 63, w = threadIdx.x >> 6;
    int pl = lane & 15, q4 = lane >> 4;
    int p = w * 16 + pl;
    f32x4 acc[4][2];
#pragma unroll
    for (int r = 0; r < 4; ++r) { acc[r][0] = (f32x4)0.f; acc[r][1] = (f32x4)0.f; }
#pragma unroll
    for (int kk = 0; kk < 9; ++kk) {
        int dy = kk / 3, dx = kk % 3;
        int xx = p + dx;
#pragma unroll
        for (int ch = 0; ch < 2; ++ch) {
            short8 bfr[4];
#pragma unroll
            for (int r = 0; r < 4; ++r) bfr[r] = read_b6(xls, dy + r, xx, ch * 32 + q4 * 8);
#pragma unroll
            for (int cp = 0; cp < 2; ++cp) {
                short8 afr = *(const short8*)(W2 + ((kk * 32 + cp * 16 + pl) * 64 + ch * 32 + q4 * 8));
#pragma unroll
                for (int r = 0; r < 4; ++r)
                    acc[r][cp] = __builtin_amdgcn_mfma_f32_16x16x32_bf16(afr, bfr[r], acc[r][cp], 0, 0, 0);
            }
        }
    }
#pragma unroll
    for (int r = 0; r < 4; ++r) {
        size_t pglob = (size_t)(b * HWc + (y0 + r) * Wc + x0 + p);
#pragma unroll
        for (int cp = 0; cp < 2; ++cp) {
            int co0 = cp * 16 + q4 * 4;
            f32x4 rr;
#pragma unroll
            for (int j = 0; j < 4; ++j) {
                float bias = (co0 + j < 27) ? b2[co0 + j] : 0.f;
                rr[j] = acc[r][cp][j] + bias;
            }
            *(f32x4*)(headT + pglob * 32 + co0) = rr;
        }
    }
}

// ---- mdcn_g: one-shot full-K gather -> LDS val -> K=576 MFMA -> fdreluT ----
// Block = 32 px of one row, 128 threads. Gather: 288 (px,kk) tasks sample all
// 64 ch from global (clamped coords, zero weights when invalid -> no fallback,
// no branches). val LDS [32px][9kk][64ch] bf16 = 36864 B, XOR ^((px&7)<<4).
// One barrier, then 18 K-step MFMA loop.
__global__ __launch_bounds__(128) void mdcn_g(const unsigned short* __restrict__ depthT,
                                              const float* __restrict__ headT,
                                              const char* __restrict__ ws,
                                              const float* __restrict__ bd,
                                              unsigned short* __restrict__ fdreluT) {
    __shared__ __align__(16) unsigned short vls[32 * 576];   // 36864 B
    const unsigned short* WD = (const unsigned short*)(ws + B_WD);
    int blk = swz_blk(blockIdx.x, 480);          // 3840 blocks
    int xt = blk % 10, y = (blk / 10) % 96, b = blk / 960;
    int x0 = xt * 32;
    int lane = threadIdx.x & 63, w = threadIdx.x >> 6;   // w in {0,1}
    size_t dbase = (size_t)b * HWc * 64;
    size_t rowbase = (size_t)(b * HWc + y * Wc + x0);

    // ---- gather phase: 144 tasks per wave, fully independent ----
#pragma unroll
    for (int it = 0; it < 3; ++it) {
        int idx = it * 64 + lane;
        if (idx < 144) {
            int task = w * 144 + idx;            // 0..287
            int px = task & 31, kk = task >> 5;  // task = kk*32 + px
            const float* hd = headT + (rowbase + px) * 32;
            float dyv = hd[2 * kk], dxv = hd[2 * kk + 1], sm = hd[18 + kk];
            float m = 1.f / (1.f + __expf(-sm));
            float py  = (float)(y + kk / 3 - 1) + dyv;
            float pxf = (float)(x0 + px + kk % 3 - 1) + dxv;
            float y0f = floorf(py), x0f = floorf(pxf);
            float wy = py - y0f, wx = pxf - x0f;
            int iy0 = (int)y0f, ix0 = (int)x0f;
            bool vy0 = (unsigned)iy0 < 96u, vy1 = (unsigned)(iy0 + 1) < 96u;
            bool vx0 = (unsigned)ix0 < 320u, vx1 = (unsigned)(ix0 + 1) < 320u;
            int cy0 = min(max(iy0, 0), 95),  cy1 = min(max(iy0 + 1, 0), 95);
            int cx0 = min(max(ix0, 0), 319), cx1 = min(max(ix0 + 1, 0), 319);
            float w00 = (vy0 && vx0) ? (1.f - wy) * (1.f - wx) * m : 0.f;
            float w01 = (vy0 && vx1) ? (1.f - wy) * wx * m : 0.f;
            float w10 = (vy1 && vx0) ? wy * (1.f - wx) * m : 0.f;
            float w11 = (vy1 && vx1) ? wy * wx * m : 0.f;
            const unsigned short* r00 = depthT + dbase + (size_t)(cy0 * Wc + cx0) * 64;
            const unsigned short* r01 = depthT + dbase + (size_t)(cy0 * Wc + cx1) * 64;
            const unsigned short* r10 = depthT + dbase + (size_t)(cy1 * Wc + cx0) * 64;
            const unsigned short* r11 = depthT + dbase + (size_t)(cy1 * Wc + cx1) * 64;
            int base = px * 1152 + kk * 128;     // byte base of this (px,kk) row
#pragma unroll
            for (int c8 = 0; c8 < 8; ++c8) {
                short8 f00 = *(const short8*)(r00 + c8 * 8);
                short8 f01 = *(const short8*)(r01 + c8 * 8);
                short8 f10 = *(const short8*)(r10 + c8 * 8);
                short8 f11 = *(const short8*)(r11 + c8 * 8);
                unsigned short vv[8];
#pragma unroll
                for (int j = 0; j < 8; ++j) {
                    float v = w00 * bf2f((unsigned short)f00[j]) + w01 * bf2f((unsigned short)f01[j])
                            + w10 * bf2f((unsigned short)f10[j]) + w11 * bf2f((unsigned short)f11[j]);
                    vv[j] = f2bf(v);
                }
                int byte = (base + c8 * 16) ^ ((px & 7) << 4);
                *(short8*)((char*)vls + byte) = *(short8*)vv;
            }
        }
    }
    __syncthreads();

    // ---- GEMM phase: K = 576 ----
    int pl = lane & 15, q4 = lane >> 4;
    int p = w * 16 + pl;                         // px 0..31
    f32x4 acc[4];
#pragma unroll
    for (int cp = 0; cp < 4; ++cp) acc[cp] = (f32x4)0.f;
#pragma unroll
    for (int s = 0; s < 18; ++s) {
        int kk = s >> 1, hf = s & 1;
        int byte = (p * 1152 + kk * 128 + hf * 64 + q4 * 16) ^ ((p & 7) << 4);
        short8 bfr = *(const short8*)((const char*)vls + byte);
#pragma unroll
        for (int cp = 0; cp < 4; ++cp) {
            short8 afr = *(const short8*)(WD + ((kk * 64 + cp * 16 + pl) * 64 + hf * 32 + q4 * 8));
            acc[cp] = __builtin_amdgcn_mfma_f32_16x16x32_bf16(afr, bfr, acc[cp], 0, 0, 0);
        }
    }

    // ---- epilogue: fdrelu = relu(acc + bd + depth) -> bf16 [pix][64] ----
    size_t pglob = rowbase + p;
#pragma unroll
    for (int cp = 0; cp < 4; ++cp) {
        int co0 = cp * 16 + q4 * 4;
        f32x4 bdv = *(const f32x4*)(bd + co0);
        uint2 dres = *(const uint2*)(depthT + pglob * 64 + co0);   // 4 bf16 residual
        unsigned short d4[4] = { (unsigned short)(dres.x & 0xffff), (unsigned short)(dres.x >> 16),
                                 (unsigned short)(dres.y & 0xffff), (unsigned short)(dres.y >> 16) };
        unsigned short h4[4];
#pragma unroll
        for (int j = 0; j < 4; ++j) {
            float r = acc[cp][j] + bdv[j] + bf2f(d4[j]);
            h4[j] = f2bf(fmaxf(r, 0.f));
        }
        uint2 u;
        u.x = (unsigned)h4[0] | ((unsigned)h4[1] << 16);
        u.y = (unsigned)h4[2] | ((unsigned)h4[3] << 16);
        *(uint2*)(fdreluT + pglob * 64 + co0) = u;
    }
}

// ---------------- convf: 128->64 + BN + relu -> hT  (4-row blocks) ----------------
__global__ __launch_bounds__(256) void convf_m(const unsigned short* __restrict__ fdreluT,
                                               const unsigned short* __restrict__ rgbT,
                                               const char* __restrict__ ws,
                                               unsigned short* __restrict__ hT) {
    __shared__ __align__(16) unsigned short xls[6 * 66 * 64];
    const unsigned short* WF = (const unsigned short*)(ws + B_WF);
    const float* AB = (const float*)(ws + B_AB);
    int blk = swz_blk(blockIdx.x, 60);
    int xt = blk % 5, yt = (blk / 5) % 24, b = blk / 120;
    int x0 = xt * 64, y0 = yt * 4;
    int lane = threadIdx.x & 63, w = threadIdx.x >> 6;
    int pl = lane & 15, q4 = lane >> 4;
    int p = w * 16 + pl;
    f32x4 acc[4][4];
#pragma unroll
    for (int r = 0; r < 4; ++r)
#pragma unroll
        for (int cp = 0; cp < 4; ++cp) acc[r][cp] = (f32x4)0.f;
#pragma unroll
    for (int half = 0; half < 2; ++half) {
        if (half) __syncthreads();
        stage6(half ? rgbT : fdreluT, b, y0, x0, xls, half != 0);
        __syncthreads();
        const unsigned short* Wh = WF + half * 36864;
#pragma unroll
        for (int kk = 0; kk < 9; ++kk) {
            int dy = kk / 3, dx = kk % 3;
            int xx = p + dx;
#pragma unroll
            for (int ch = 0; ch < 2; ++ch) {
                short8 bfr[4];
#pragma unroll
                for (int r = 0; r < 4; ++r) bfr[r] = read_b6(xls, dy + r, xx, ch * 32 + q4 * 8);
#pragma unroll
                for (int cp = 0; cp < 4; ++cp) {
                    short8 afr = *(const short8*)(Wh + ((kk * 64 + cp * 16 + pl) * 64 + ch * 32 + q4 * 8));
#pragma unroll
                    for (int r = 0; r < 4; ++r)
                        acc[r][cp] = __builtin_amdgcn_mfma_f32_16x16x32_bf16(afr, bfr[r], acc[r][cp], 0, 0, 0);
                }
            }
        }
    }
#pragma unroll
    for (int r = 0; r < 4; ++r) {
        size_t pglob = (size_t)(b * HWc + (y0 + r) * Wc + x0 + p);
#pragma unroll
        for (int cp = 0; cp < 4; ++cp) {
            int co0 = cp * 16 + q4 * 4;
            f32x4 a2 = *(const f32x4*)(AB + 128 + co0);
            f32x4 b2 = *(const f32x4*)(AB + 192 + co0);
            unsigned short h4[4];
#pragma unroll
            for (int j = 0; j < 4; ++j) h4[j] = f2bf(fmaxf(fmaf(acc[r][cp][j], a2[j], b2[j]), 0.f));
            uint2 u;
            u.x = (unsigned)h4[0] | ((unsigned)h4[1] << 16);
            u.y = (unsigned)h4[2] | ((unsigned)h4[3] << 16);
            *(uint2*)(hT + pglob * 64 + co0) = u;
        }
    }
}

// ---------------- conv_out: 64->1 ----------------
__global__ __launch_bounds__(256) void convo_m(const unsigned short* __restrict__ hT,
                                               const float* __restrict__ wo,
                                               const float* __restrict__ bo,
                                               float* __restrict__ out) {
    __shared__ float wl[576];
    for (int i = threadIdx.x; i < 576; i += 256) wl[i] = wo[i];
    __syncthreads();
    int p = swz_blk(blockIdx.x, 60) * 256 + threadIdx.x;   // 0..122879
    int xw = p % Wc, rem = p / Wc, y = rem % Hc, b = rem / Hc;
    float acc = bo[0];
#pragma unroll
    for (int kk = 0; kk < 9; ++kk) {
        int iy = y + kk / 3 - 1, ix = xw + kk % 3 - 1;
        if ((unsigned)iy < 96u && (unsigned)ix < 320u) {
            const unsigned short* base = hT + ((size_t)(b * HWc + iy * Wc + ix)) * 64;
#pragma unroll
            for (int g = 0; g < 8; ++g) {
                short8 v = *(const short8*)(base + g * 8);
#pragma unroll
                for (int j = 0; j < 8; ++j)
                    acc = fmaf(bf2f((unsigned short)v[j]), wl[(g * 8 + j) * 9 + kk], acc);
            }
        }
    }
    out[p] = acc;
}

// ---------------- launch ----------------
extern "C" void kernel_launch(void* const* d_in, const int* in_sizes, int n_in,
                              void* d_out, int out_size, void* d_ws, size_t ws_size,
                              hipStream_t stream) {
    const float* feat_rgb   = (const float*)d_in[0];
    const float* feat_depth = (const float*)d_in[1];
    const float* w_off1 = (const float*)d_in[2];
    const float* b_off1 = (const float*)d_in[3];
    const float* g1  = (const float*)d_in[4];
    const float* be1 = (const float*)d_in[5];
    const float* m1  = (const float*)d_in[6];
    const float* v1  = (const float*)d_in[7];
    const float* w_off2 = (const float*)d_in[8];
    const float* b_off2 = (const float*)d_in[9];
    const float* w_def  = (const float*)d_in[10];
    const float* b_def  = (const float*)d_in[11];
    const float* w_f1   = (const float*)d_in[12];
    const float* b_f1   = (const float*)d_in[13];
    const float* g2  = (const float*)d_in[14];
    const float* be2 = (const float*)d_in[15];
    const float* m2  = (const float*)d_in[16];
    const float* v2  = (const float*)d_in[17];
    const float* w_out = (const float*)d_in[18];
    const float* b_out = (const float*)d_in[19];
    (void)in_sizes; (void)n_in; (void)out_size; (void)ws_size;

    char* ws = (char*)d_ws;
    unsigned short* rgbT   = (unsigned short*)(ws + B_RGBT);
    unsigned short* depthT = (unsigned short*)(ws + B_DEPT);
    unsigned short* tT     = (unsigned short*)(ws + B_TT);
    float*          headT  = (float*)(ws + B_HEAD);
    unsigned short* fdreluT = tT;       // reuse (tT dead after conv2)
    unsigned short* hT      = depthT;   // reuse (depthT dead after mdcn)

    prep_w<<<64, 256, 0, stream>>>(w_off1, b_off1, g1, be1, m1, v1,
                                   w_off2, w_def, w_f1, b_f1, g2, be2, m2, v2, ws);
    prep_x2<<<NPIX / 64, 256, 0, stream>>>(feat_rgb, feat_depth, rgbT, depthT);
    conv1_m<<<480, 256, 0, stream>>>(rgbT, ws, tT);
    conv2_m<<<480, 256, 0, stream>>>(ws, b_off2, headT, tT);
    mdcn_g <<<3840, 128, 0, stream>>>(depthT, headT, ws, b_def, fdreluT);
    convf_m<<<480, 256, 0, stream>>>(fdreluT, rgbT, ws, hT);
    convo_m<<<480, 256, 0, stream>>>(hT, w_out, b_out, (float*)d_out);
}

// Round 12
// 376.003 us; speedup vs baseline: 1.1594x; 1.1594x over previous
//
#include <hip/hip_runtime.h>
#include <math.h>

// ---------------- problem constants ----------------
constexpr int Bc  = 4;
constexpr int Hc  = 96;
constexpr int Wc  = 320;
constexpr int HWc = Hc * Wc;           // 30720
constexpr int NPIX = Bc * HWc;         // 122880

typedef __attribute__((ext_vector_type(8))) short short8;   // 8 x bf16 fragment
typedef __attribute__((ext_vector_type(4))) float f32x4;    // mfma acc

// ---------------- workspace byte offsets ----------------
constexpr size_t B_W1   = 0;                    // bf16 [9][64co][64ci]   73728 B
constexpr size_t B_W2   = 73728;                // bf16 [9][32co][64ci]   36864 B
constexpr size_t B_WD   = 110592;               // bf16 [9][64o][64c]     73728 B
constexpr size_t B_WF   = 184320;               // bf16 [2][9][64co][64ci]147456 B
constexpr size_t B_AB   = 331776;               // f32 A1,B1,A2,B2        1024 B
constexpr size_t B_RGBT = 332800;               // bf16 [pix][64]         15728640 B
constexpr size_t B_DEPT = 16061440;             // bf16 [pix][64]  (later reused as hT)
constexpr size_t B_TT   = 31790080;             // bf16 [pix][64]  (later reused as fdreluT)
constexpr size_t B_HEAD = 47518720;             // f32  [pix][32]         15728640 B

// ---------------- helpers ----------------
static __device__ __forceinline__ unsigned short f2bf(float f) {
    unsigned u = __builtin_bit_cast(unsigned, f);
    u = (u + 0x7fffu + ((u >> 16) & 1u)) >> 16;   // RNE
    return (unsigned short)u;
}
static __device__ __forceinline__ float bf2f(unsigned short h) {
    unsigned u = ((unsigned)h) << 16;
    return __builtin_bit_cast(float, u);
}
// XCD-aware block swizzle: grid divisible by 8; each XCD gets contiguous chunk.
static __device__ __forceinline__ int swz_blk(int bid, int chunk) {
    return (bid & 7) * chunk + (bid >> 3);
}

// ---------------- prep: weights + BN folds ----------------
__global__ void prep_w(const float* __restrict__ w1, const float* __restrict__ b1,
                       const float* __restrict__ g1, const float* __restrict__ be1,
                       const float* __restrict__ m1, const float* __restrict__ v1,
                       const float* __restrict__ w2,
                       const float* __restrict__ wd,
                       const float* __restrict__ wf, const float* __restrict__ bf1,
                       const float* __restrict__ g2, const float* __restrict__ be2,
                       const float* __restrict__ m2, const float* __restrict__ v2,
                       char* __restrict__ ws) {
    int tid = blockIdx.x * blockDim.x + threadIdx.x;
    int stride = gridDim.x * blockDim.x;
    unsigned short* W1 = (unsigned short*)(ws + B_W1);
    unsigned short* W2 = (unsigned short*)(ws + B_W2);
    unsigned short* WD = (unsigned short*)(ws + B_WD);
    unsigned short* WF = (unsigned short*)(ws + B_WF);
    float* AB = (float*)(ws + B_AB);
    for (int i = tid; i < 36864; i += stride) {         // W1p [kk][co][ci]
        int ci = i & 63, co = (i >> 6) & 63, kk = i >> 12;
        W1[i] = f2bf(w1[(co * 64 + ci) * 9 + kk]);
    }
    for (int i = tid; i < 18432; i += stride) {         // W2p [kk][32co][ci]
        int ci = i & 63, co = (i >> 6) & 31, kk = i >> 11;
        W2[i] = (co < 27) ? f2bf(w2[(co * 64 + ci) * 9 + kk]) : (unsigned short)0;
    }
    for (int i = tid; i < 36864; i += stride) {         // Wdp [kk][o][c]
        int c = i & 63, o = (i >> 6) & 63, kk = i >> 12;
        WD[i] = f2bf(wd[(o * 64 + c) * 9 + kk]);
    }
    for (int i = tid; i < 73728; i += stride) {         // Wfp [half][kk][co][ci]
        int ci = i & 63, co = (i >> 6) & 63, r = i >> 12;
        int kk = r % 9, h = r / 9;
        WF[i] = f2bf(wf[(co * 128 + h * 64 + ci) * 9 + kk]);
    }
    if (tid < 64) {
        float s1 = g1[tid] / sqrtf(v1[tid] + 1e-5f);
        AB[tid]        = s1;
        AB[64 + tid]   = b1[tid] * s1 + be1[tid] - m1[tid] * s1;
        float s2 = g2[tid] / sqrtf(v2[tid] + 1e-5f);
        AB[128 + tid]  = s2;
        AB[192 + tid]  = bf1[tid] * s2 + be2[tid] - m2[tid] * s2;
    }
}

// ---- prep_x2: coalesced f32 read -> LDS transpose -> coalesced bf16 write ----
// One block = 64 consecutive pixels (never crosses batch; 30720 % 64 == 0).
__global__ __launch_bounds__(256) void prep_x2(const float* __restrict__ rgb,
                                               const float* __restrict__ dep,
                                               unsigned short* __restrict__ rgbT,
                                               unsigned short* __restrict__ depT) {
    __shared__ unsigned short tr[64 * 66];     // [p][ch], stride 66 (bank-safe both sides)
    int pg0 = blockIdx.x * 64;
    int b = pg0 / HWc, pix0 = pg0 % HWc;
    const float* srcs[2] = { rgb, dep };
    unsigned short* dsts[2] = { rgbT, depT };
#pragma unroll
    for (int which = 0; which < 2; ++which) {
        if (which) __syncthreads();            // WAR vs previous read phase
        const float* src = srcs[which];
#pragma unroll
        for (int it = 0; it < 16; ++it) {
            int idx = it * 256 + threadIdx.x;
            int p = idx & 63, ch = idx >> 6;
            float v = src[((size_t)b * 64 + ch) * HWc + pix0 + p];
            tr[p * 66 + ch] = f2bf(v);
        }
        __syncthreads();
        unsigned short* dst = dsts[which];
#pragma unroll
        for (int it = 0; it < 2; ++it) {
            int q = it * 256 + threadIdx.x;
            int p = q >> 3, g = q & 7;
            const char* basep = (const char*)tr + p * 132 + g * 16;   // 4-aligned
            uint4 u;
            u.x = *(const unsigned*)(basep + 0);
            u.y = *(const unsigned*)(basep + 4);
            u.z = *(const unsigned*)(basep + 8);
            u.w = *(const unsigned*)(basep + 12);
            *(uint4*)(dst + (size_t)(pg0 + p) * 64 + g * 8) = u;
        }
    }
}

// ------------- LDS staging: 6-row halo tile, 32 channels per pass -------------
// LDS layout: [6 rows][66 xx][32 ci] bf16 = 25344 B, byte ^= ((xx&7)<<4).
// Halved vs 64-ch so 2x blocks/CU; conv kernels run 2 channel passes.
static __device__ __forceinline__ void stage6h(const unsigned short* __restrict__ src,
                                               int b, int y0, int x0,
                                               unsigned short* lds, bool do_relu, int ch0) {
#pragma unroll
    for (int it = 0; it < 7; ++it) {
        int i = threadIdx.x + it * 256;
        if (i < 1584) {                       // 6*66*4 chunks of 8ch
            int g = i & 3;
            int xx = (i >> 2) % 66;
            int row = (i >> 2) / 66;
            int y = y0 - 1 + row, x = x0 - 1 + xx;
            short8 v = (short8)0;
            if ((unsigned)y < 96u && (unsigned)x < 320u) {
                v = *(const short8*)(src + ((size_t)(b * HWc + y * Wc + x)) * 64 + ch0 + g * 8);
            }
            if (do_relu) {
#pragma unroll
                for (int j = 0; j < 8; ++j) {
                    short s = v[j];
                    v[j] = (s & (short)0x8000) ? (short)0 : s;
                }
            }
            int byte = ((row * 66 + xx) * 32 + g * 8) * 2;
            byte ^= ((xx & 7) << 4);
            *(short8*)((char*)lds + byte) = v;
        }
    }
}

static __device__ __forceinline__ short8 read_b6h(const unsigned short* lds, int row, int xx, int c) {
    int byte = ((row * 66 + xx) * 32 + c) * 2;
    byte ^= ((xx & 7) << 4);
    return *(const short8*)((const char*)lds + byte);
}

// ------------ conv1: 64->64 + BN, rgbT -> tT  (4-row blocks, 2 ch-passes) ------------
__global__ __launch_bounds__(256) void conv1_m(const unsigned short* __restrict__ rgbT,
                                               const char* __restrict__ ws,
                                               unsigned short* __restrict__ tT) {
    __shared__ __align__(16) unsigned short xls[6 * 66 * 32];
    const unsigned short* W1 = (const unsigned short*)(ws + B_W1);
    const float* AB = (const float*)(ws + B_AB);
    int blk = swz_blk(blockIdx.x, 60);        // 480 blocks
    int xt = blk % 5, yt = (blk / 5) % 24, b = blk / 120;
    int x0 = xt * 64, y0 = yt * 4;
    int lane = threadIdx.x & 63, w = threadIdx.x >> 6;
    int pl = lane & 15, q4 = lane >> 4;
    int p = w * 16 + pl;
    f32x4 acc[4][4];                          // [row][cp]
#pragma unroll
    for (int r = 0; r < 4; ++r)
#pragma unroll
        for (int cp = 0; cp < 4; ++cp) acc[r][cp] = (f32x4)0.f;
#pragma unroll
    for (int chp = 0; chp < 2; ++chp) {
        if (chp) __syncthreads();             // WAR vs previous pass reads
        stage6h(rgbT, b, y0, x0, xls, false, chp * 32);
        __syncthreads();
#pragma unroll
        for (int kk = 0; kk < 9; ++kk) {
            int dy = kk / 3, dx = kk % 3;
            int xx = p + dx;
            short8 bfr[4];
#pragma unroll
            for (int r = 0; r < 4; ++r) bfr[r] = read_b6h(xls, dy + r, xx, q4 * 8);
#pragma unroll
            for (int cp = 0; cp < 4; ++cp) {
                short8 afr = *(const short8*)(W1 + ((kk * 64 + cp * 16 + pl) * 64 + chp * 32 + q4 * 8));
#pragma unroll
                for (int r = 0; r < 4; ++r)
                    acc[r][cp] = __builtin_amdgcn_mfma_f32_16x16x32_bf16(afr, bfr[r], acc[r][cp], 0, 0, 0);
            }
        }
    }
#pragma unroll
    for (int r = 0; r < 4; ++r) {
        size_t pglob = (size_t)(b * HWc + (y0 + r) * Wc + x0 + p);
#pragma unroll
        for (int cp = 0; cp < 4; ++cp) {
            int co0 = cp * 16 + q4 * 4;
            f32x4 a1 = *(const f32x4*)(AB + co0);
            f32x4 b1 = *(const f32x4*)(AB + 64 + co0);
            unsigned short h4[4];
#pragma unroll
            for (int j = 0; j < 4; ++j) h4[j] = f2bf(fmaf(acc[r][cp][j], a1[j], b1[j]));
            uint2 u;
            u.x = (unsigned)h4[0] | ((unsigned)h4[1] << 16);
            u.y = (unsigned)h4[2] | ((unsigned)h4[3] << 16);
            *(uint2*)(tT + pglob * 64 + co0) = u;
        }
    }
}

// -------- conv2: 64->27(pad32), tT -> headT (f32)  (4-row blocks, 2 ch-passes) --------
__global__ __launch_bounds__(256) void conv2_m(const char* __restrict__ ws,
                                               const float* __restrict__ b2,
                                               float* __restrict__ headT,
                                               const unsigned short* __restrict__ tT) {
    __shared__ __align__(16) unsigned short xls[6 * 66 * 32];
    const unsigned short* W2 = (const unsigned short*)(ws + B_W2);
    int blk = swz_blk(blockIdx.x, 60);
    int xt = blk % 5, yt = (blk / 5) % 24, b = blk / 120;
    int x0 = xt * 64, y0 = yt * 4;
    int lane = threadIdx.x & 63, w = threadIdx.x >> 6;
    int pl = lane & 15, q4 = lane >> 4;
    int p = w * 16 + pl;
    f32x4 acc[4][2];
#pragma unroll
    for (int r = 0; r < 4; ++r) { acc[r][0] = (f32x4)0.f; acc[r][1] = (f32x4)0.f; }
#pragma unroll
    for (int chp = 0; chp < 2; ++chp) {
        if (chp) __syncthreads();
        stage6h(tT, b, y0, x0, xls, false, chp * 32);
        __syncthreads();
#pragma unroll
        for (int kk = 0; kk < 9; ++kk) {
            int dy = kk / 3, dx = kk % 3;
            int xx = p + dx;
            short8 bfr[4];
#pragma unroll
            for (int r = 0; r < 4; ++r) bfr[r] = read_b6h(xls, dy + r, xx, q4 * 8);
#pragma unroll
            for (int cp = 0; cp < 2; ++cp) {
                short8 afr = *(const short8*)(W2 + ((kk * 32 + cp * 16 + pl) * 64 + chp * 32 + q4 * 8));
#pragma unroll
                for (int r = 0; r < 4; ++r)
                    acc[r][cp] = __builtin_amdgcn_mfma_f32_16x16x32_bf16(afr, bfr[r], acc[r][cp], 0, 0, 0);
            }
        }
    }
#pragma unroll
    for (int r = 0; r < 4; ++r) {
        size_t pglob = (size_t)(b * HWc + (y0 + r) * Wc + x0 + p);
#pragma unroll
        for (int cp = 0; cp < 2; ++cp) {
            int co0 = cp * 16 + q4 * 4;
            f32x4 rr;
#pragma unroll
            for (int j = 0; j < 4; ++j) {
                float bias = (co0 + j < 27) ? b2[co0 + j] : 0.f;
                rr[j] = acc[r][cp][j] + bias;
            }
            *(f32x4*)(headT + pglob * 32 + co0) = rr;
        }
    }
}

// ---- mdcn: LDS-windowed gather (global fallback) + 576-K GEMM -> fdreluT ----
// Window per block: rows [y-5,y+5] x cols [x0-5,x0+68], half channels per pass.
// LDS [11][74][32ch] bf16 = 52096 B; byte = ((r*74+c)*64 + sub*16) ^ ((c&6)<<3)
__global__ __launch_bounds__(256) void mdcn_l(const unsigned short* __restrict__ depthT,
                                              const float* __restrict__ headT,
                                              const char* __restrict__ ws,
                                              const float* __restrict__ bd,
                                              unsigned short* __restrict__ fdreluT) {
    __shared__ __align__(16) unsigned short vls[26048];   // 11*74*32
    const unsigned short* WD = (const unsigned short*)(ws + B_WD);
    int blk = swz_blk(blockIdx.x, 240);
    int xt = blk % 5, y = (blk / 5) % 96, b = blk / 480;
    int x0 = xt * 64;
    int lane = threadIdx.x & 63, w = threadIdx.x >> 6;
    int pl = lane & 15, q4 = lane >> 4;
    int p = w * 16 + pl;
    int px = x0 + p;
    size_t pglob = (size_t)(b * HWc + y * Wc + px);
    size_t dbase = (size_t)b * HWc * 64;
    const float* hd = headT + pglob * 32;
    float hv[28];
#pragma unroll
    for (int i = 0; i < 7; ++i) {
        f32x4 t = *(const f32x4*)(hd + i * 4);
        hv[i * 4 + 0] = t[0]; hv[i * 4 + 1] = t[1];
        hv[i * 4 + 2] = t[2]; hv[i * 4 + 3] = t[3];
    }
    f32x4 acc[4];
#pragma unroll
    for (int cp = 0; cp < 4; ++cp) acc[cp] = (f32x4)0.f;

    const int wy0 = y - 5;          // window row origin
    const int wx0 = x0 - 5;         // window col origin

#pragma unroll
    for (int pass = 0; pass < 2; ++pass) {
        // ---- stage window (32 channels) ----
        if (pass) __syncthreads();  // WAR vs pass-0 reads
#pragma unroll
        for (int it = 0; it < 13; ++it) {
            int i = threadIdx.x + it * 256;
            if (i < 3256) {                    // 11*74*4 chunks of 16B
                int sub = i & 3;
                int c = (i >> 2) % 74;
                int r = (i >> 2) / 74;
                int gy = wy0 + r, gx = wx0 + c;
                short8 v = (short8)0;
                if ((unsigned)gy < 96u && (unsigned)gx < 320u)
                    v = *(const short8*)(depthT + ((size_t)(b * HWc + gy * Wc + gx)) * 64 + pass * 32 + sub * 8);
                int byte = (((r * 74 + c) * 64) + sub * 16) ^ ((c & 6) << 3);
                *(short8*)((char*)vls + byte) = v;
            }
        }
        __syncthreads();
        // ---- 9 kernel points ----
#pragma unroll
        for (int kk = 0; kk < 9; ++kk) {
            float dyv = hv[2 * kk], dxv = hv[2 * kk + 1], sm = hv[18 + kk];
            float m = 1.f / (1.f + __expf(-sm));
            float py  = (float)(y + kk / 3 - 1) + dyv;
            float pxf = (float)(px + kk % 3 - 1) + dxv;
            float y0f = floorf(py), x0f = floorf(pxf);
            float wy = py - y0f, wx = pxf - x0f;
            int iy0 = (int)y0f, ix0 = (int)x0f;
            bool vy0 = (unsigned)iy0 < 96u, vy1 = (unsigned)(iy0 + 1) < 96u;
            bool vx0 = (unsigned)ix0 < 320u, vx1 = (unsigned)(ix0 + 1) < 320u;
            int cy0 = min(max(iy0, 0), 95),  cy1 = min(max(iy0 + 1, 0), 95);
            int cx0 = min(max(ix0, 0), 319), cx1 = min(max(ix0 + 1, 0), 319);
            float w00 = (vy0 && vx0) ? (1.f - wy) * (1.f - wx) * m : 0.f;
            float w01 = (vy0 && vx1) ? (1.f - wy) * wx * m : 0.f;
            float w10 = (vy1 && vx0) ? wy * (1.f - wx) * m : 0.f;
            float w11 = (vy1 && vx1) ? wy * wx * m : 0.f;
            // in-window iff iy0 in [y-5, y+4] and ix0 in [x0-5, x0+67]
            bool inw = ((unsigned)(iy0 - wy0) <= 9u) && ((unsigned)(ix0 - wx0) <= 72u);
            // clamped local coords (bogus lanes read slot 0 harmlessly)
            int lr0 = min(max(cy0 - wy0, 0), 10), lr1 = min(max(cy1 - wy0, 0), 10);
            int lc0 = min(max(cx0 - wx0, 0), 73), lc1 = min(max(cx1 - wx0, 0), 73);
            int qb = q4 * 16;
            short8 f00 = *(const short8*)((const char*)vls + ((((lr0 * 74 + lc0) * 64) + qb) ^ ((lc0 & 6) << 3)));
            short8 f01 = *(const short8*)((const char*)vls + ((((lr0 * 74 + lc1) * 64) + qb) ^ ((lc1 & 6) << 3)));
            short8 f10 = *(const short8*)((const char*)vls + ((((lr1 * 74 + lc0) * 64) + qb) ^ ((lc0 & 6) << 3)));
            short8 f11 = *(const short8*)((const char*)vls + ((((lr1 * 74 + lc1) * 64) + qb) ^ ((lc1 & 6) << 3)));
            if (!__all(inw)) {                 // rare: offsets beyond +-4
                if (!inw) {
                    const unsigned short* bp = depthT + dbase + pass * 32 + q4 * 8;
                    f00 = *(const short8*)(bp + (size_t)(cy0 * Wc + cx0) * 64);
                    f01 = *(const short8*)(bp + (size_t)(cy0 * Wc + cx1) * 64);
                    f10 = *(const short8*)(bp + (size_t)(cy1 * Wc + cx0) * 64);
                    f11 = *(const short8*)(bp + (size_t)(cy1 * Wc + cx1) * 64);
                }
            }
            unsigned short vv[8];
#pragma unroll
            for (int j = 0; j < 8; ++j) {
                float v = w00 * bf2f((unsigned short)f00[j]) + w01 * bf2f((unsigned short)f01[j])
                        + w10 * bf2f((unsigned short)f10[j]) + w11 * bf2f((unsigned short)f11[j]);
                vv[j] = f2bf(v);
            }
            short8 bfr = *(short8*)vv;
#pragma unroll
            for (int cp = 0; cp < 4; ++cp) {
                short8 afr = *(const short8*)(WD + ((kk * 64 + cp * 16 + pl) * 64 + pass * 32 + q4 * 8));
                acc[cp] = __builtin_amdgcn_mfma_f32_16x16x32_bf16(afr, bfr, acc[cp], 0, 0, 0);
            }
        }
    }
    // epilogue: fdrelu = relu(acc + bd + depth) -> bf16 [pix][64]
#pragma unroll
    for (int cp = 0; cp < 4; ++cp) {
        int co0 = cp * 16 + q4 * 4;
        f32x4 bdv = *(const f32x4*)(bd + co0);
        uint2 dres = *(const uint2*)(depthT + pglob * 64 + co0);   // 4 bf16 residual
        unsigned short d4[4] = { (unsigned short)(dres.x & 0xffff), (unsigned short)(dres.x >> 16),
                                 (unsigned short)(dres.y & 0xffff), (unsigned short)(dres.y >> 16) };
        unsigned short h4[4];
#pragma unroll
        for (int j = 0; j < 4; ++j) {
            float r = acc[cp][j] + bdv[j] + bf2f(d4[j]);
            h4[j] = f2bf(fmaxf(r, 0.f));
        }
        uint2 u;
        u.x = (unsigned)h4[0] | ((unsigned)h4[1] << 16);
        u.y = (unsigned)h4[2] | ((unsigned)h4[3] << 16);
        *(uint2*)(fdreluT + pglob * 64 + co0) = u;
    }
}

// ------- convf: 128->64 + BN + relu -> hT  (4-row blocks, 4 ch-passes) -------
__global__ __launch_bounds__(256) void convf_m(const unsigned short* __restrict__ fdreluT,
                                               const unsigned short* __restrict__ rgbT,
                                               const char* __restrict__ ws,
                                               unsigned short* __restrict__ hT) {
    __shared__ __align__(16) unsigned short xls[6 * 66 * 32];
    const unsigned short* WF = (const unsigned short*)(ws + B_WF);
    const float* AB = (const float*)(ws + B_AB);
    int blk = swz_blk(blockIdx.x, 60);
    int xt = blk % 5, yt = (blk / 5) % 24, b = blk / 120;
    int x0 = xt * 64, y0 = yt * 4;
    int lane = threadIdx.x & 63, w = threadIdx.x >> 6;
    int pl = lane & 15, q4 = lane >> 4;
    int p = w * 16 + pl;
    f32x4 acc[4][4];
#pragma unroll
    for (int r = 0; r < 4; ++r)
#pragma unroll
        for (int cp = 0; cp < 4; ++cp) acc[r][cp] = (f32x4)0.f;
#pragma unroll
    for (int half = 0; half < 2; ++half) {
        const unsigned short* src = half ? rgbT : fdreluT;
        const unsigned short* Wh = WF + half * 36864;
#pragma unroll
        for (int chp = 0; chp < 2; ++chp) {
            if (half || chp) __syncthreads();
            stage6h(src, b, y0, x0, xls, half != 0, chp * 32);
            __syncthreads();
#pragma unroll
            for (int kk = 0; kk < 9; ++kk) {
                int dy = kk / 3, dx = kk % 3;
                int xx = p + dx;
                short8 bfr[4];
#pragma unroll
                for (int r = 0; r < 4; ++r) bfr[r] = read_b6h(xls, dy + r, xx, q4 * 8);
#pragma unroll
                for (int cp = 0; cp < 4; ++cp) {
                    short8 afr = *(const short8*)(Wh + ((kk * 64 + cp * 16 + pl) * 64 + chp * 32 + q4 * 8));
#pragma unroll
                    for (int r = 0; r < 4; ++r)
                        acc[r][cp] = __builtin_amdgcn_mfma_f32_16x16x32_bf16(afr, bfr[r], acc[r][cp], 0, 0, 0);
                }
            }
        }
    }
#pragma unroll
    for (int r = 0; r < 4; ++r) {
        size_t pglob = (size_t)(b * HWc + (y0 + r) * Wc + x0 + p);
#pragma unroll
        for (int cp = 0; cp < 4; ++cp) {
            int co0 = cp * 16 + q4 * 4;
            f32x4 a2 = *(const f32x4*)(AB + 128 + co0);
            f32x4 b2 = *(const f32x4*)(AB + 192 + co0);
            unsigned short h4[4];
#pragma unroll
            for (int j = 0; j < 4; ++j) h4[j] = f2bf(fmaxf(fmaf(acc[r][cp][j], a2[j], b2[j]), 0.f));
            uint2 u;
            u.x = (unsigned)h4[0] | ((unsigned)h4[1] << 16);
            u.y = (unsigned)h4[2] | ((unsigned)h4[3] << 16);
            *(uint2*)(hT + pglob * 64 + co0) = u;
        }
    }
}

// ---------------- conv_out: 64->1 ----------------
__global__ __launch_bounds__(256) void convo_m(const unsigned short* __restrict__ hT,
                                               const float* __restrict__ wo,
                                               const float* __restrict__ bo,
                                               float* __restrict__ out) {
    __shared__ float wl[576];
    for (int i = threadIdx.x; i < 576; i += 256) wl[i] = wo[i];
    __syncthreads();
    int p = swz_blk(blockIdx.x, 60) * 256 + threadIdx.x;   // 0..122879
    int xw = p % Wc, rem = p / Wc, y = rem % Hc, b = rem / Hc;
    float acc = bo[0];
#pragma unroll
    for (int kk = 0; kk < 9; ++kk) {
        int iy = y + kk / 3 - 1, ix = xw + kk % 3 - 1;
        if ((unsigned)iy < 96u && (unsigned)ix < 320u) {
            const unsigned short* base = hT + ((size_t)(b * HWc + iy * Wc + ix)) * 64;
#pragma unroll
            for (int g = 0; g < 8; ++g) {
                short8 v = *(const short8*)(base + g * 8);
#pragma unroll
                for (int j = 0; j < 8; ++j)
                    acc = fmaf(bf2f((unsigned short)v[j]), wl[(g * 8 + j) * 9 + kk], acc);
            }
        }
    }
    out[p] = acc;
}

// ---------------- launch ----------------
extern "C" void kernel_launch(void* const* d_in, const int* in_sizes, int n_in,
                              void* d_out, int out_size, void* d_ws, size_t ws_size,
                              hipStream_t stream) {
    const float* feat_rgb   = (const float*)d_in[0];
    const float* feat_depth = (const float*)d_in[1];
    const float* w_off1 = (const float*)d_in[2];
    const float* b_off1 = (const float*)d_in[3];
    const float* g1  = (const float*)d_in[4];
    const float* be1 = (const float*)d_in[5];
    const float* m1  = (const float*)d_in[6];
    const float* v1  = (const float*)d_in[7];
    const float* w_off2 = (const float*)d_in[8];
    const float* b_off2 = (const float*)d_in[9];
    const float* w_def  = (const float*)d_in[10];
    const float* b_def  = (const float*)d_in[11];
    const float* w_f1   = (const float*)d_in[12];
    const float* b_f1   = (const float*)d_in[13];
    const float* g2  = (const float*)d_in[14];
    const float* be2 = (const float*)d_in[15];
    const float* m2  = (const float*)d_in[16];
    const float* v2  = (const float*)d_in[17];
    const float* w_out = (const float*)d_in[18];
    const float* b_out = (const float*)d_in[19];
    (void)in_sizes; (void)n_in; (void)out_size; (void)ws_size;

    char* ws = (char*)d_ws;
    unsigned short* rgbT   = (unsigned short*)(ws + B_RGBT);
    unsigned short* depthT = (unsigned short*)(ws + B_DEPT);
    unsigned short* tT     = (unsigned short*)(ws + B_TT);
    float*          headT  = (float*)(ws + B_HEAD);
    unsigned short* fdreluT = tT;       // reuse (tT dead after conv2)
    unsigned short* hT      = depthT;   // reuse (depthT dead after mdcn)

    prep_w<<<64, 256, 0, stream>>>(w_off1, b_off1, g1, be1, m1, v1,
                                   w_off2, w_def, w_f1, b_f1, g2, be2, m2, v2, ws);
    prep_x2<<<NPIX / 64, 256, 0, stream>>>(feat_rgb, feat_depth, rgbT, depthT);
    conv1_m<<<480, 256, 0, stream>>>(rgbT, ws, tT);
    conv2_m<<<480, 256, 0, stream>>>(ws, b_off2, headT, tT);
    mdcn_l <<<1920, 256, 0, stream>>>(depthT, headT, ws, b_def, fdreluT);
    convf_m<<<480, 256, 0, stream>>>(fdreluT, rgbT, ws, hT);
    convo_m<<<480, 256, 0, stream>>>(hT, w_out, b_out, (float*)d_out);
}